// Round 5
// baseline (474.584 us; speedup 1.0000x reference)
//
#include <hip/hip_runtime.h>

#define BB 8
#define TT 4096
#define DD 768
#define MM (BB*TT)   // 32768

typedef _Float16 f16;
typedef _Float16 f16x8 __attribute__((ext_vector_type(8)));
typedef float f32x4 __attribute__((ext_vector_type(4)));

typedef __attribute__((address_space(1))) void void_g;
typedef __attribute__((address_space(3))) void void_l;

// async global->LDS, 16B per lane. LDS dest = wave-uniform base + lane*16 (linear).
__device__ __forceinline__ void gload16(const void* g, void* l) {
  __builtin_amdgcn_global_load_lds((void_g*)g, (void_l*)l, 16, 0, 0);
}

// ---------------- projection GEMM: C[m,n] = sum_k A[m,k]*W[n,k] + bias[n] --
// A: MMxDD f32, W: DDxDD f32 (both converted to f16 during reg-staging)
__global__ __launch_bounds__(256)
void proj_gemm(const float* __restrict__ Af, const float* __restrict__ Wf,
               const float* __restrict__ bias, f16* __restrict__ C) {
  __shared__ f16 As[128 * 32];
  __shared__ f16 Ws[128 * 32];
  const int m0 = blockIdx.x * 128;
  const int n0 = blockIdx.y * 128;
  const int t = threadIdx.x;
  const int lane = t & 63;
  const int w = t >> 6;
  const int wm = (w >> 1) * 64;
  const int wn = (w & 1) * 64;
  const int fr = lane & 15, fq = lane >> 4;
  const int xst = ((t >> 3) & 3) << 3;   // store-side swizzle (row = t>>2)
  const int xrd = ((fr >> 1) & 3) << 3;  // read-side swizzle (row = ..+fr)

  f32x4 acc[4][4] = {};

  const int e0 = t * 8;
  const int r0 = t >> 2, cW = (t & 3) * 8;
  const int e1 = 2048 + t * 8;

  for (int ks = 0; ks < 24; ++ks) {
    const int k0 = ks * 32;
    {
      const float* g0 = Wf + (size_t)(n0 + r0) * DD + k0 + cW;
      const float* g1 = Wf + (size_t)(n0 + 64 + r0) * DD + k0 + cW;
      float4 x0 = *(const float4*)g0, x1 = *(const float4*)(g0 + 4);
      float4 y0 = *(const float4*)g1, y1 = *(const float4*)(g1 + 4);
      f16x8 va, vb;
      va[0] = (f16)x0.x; va[1] = (f16)x0.y; va[2] = (f16)x0.z; va[3] = (f16)x0.w;
      va[4] = (f16)x1.x; va[5] = (f16)x1.y; va[6] = (f16)x1.z; va[7] = (f16)x1.w;
      vb[0] = (f16)y0.x; vb[1] = (f16)y0.y; vb[2] = (f16)y0.z; vb[3] = (f16)y0.w;
      vb[4] = (f16)y1.x; vb[5] = (f16)y1.y; vb[6] = (f16)y1.z; vb[7] = (f16)y1.w;
      *(f16x8*)&Ws[e0 ^ xst] = va;
      *(f16x8*)&Ws[e1 ^ xst] = vb;
    }
    {
      const float* g0 = Af + (size_t)(m0 + r0) * DD + k0 + cW;
      const float* g1 = Af + (size_t)(m0 + 64 + r0) * DD + k0 + cW;
      float4 x0 = *(const float4*)g0, x1 = *(const float4*)(g0 + 4);
      float4 y0 = *(const float4*)g1, y1 = *(const float4*)(g1 + 4);
      f16x8 va, vb;
      va[0] = (f16)x0.x; va[1] = (f16)x0.y; va[2] = (f16)x0.z; va[3] = (f16)x0.w;
      va[4] = (f16)x1.x; va[5] = (f16)x1.y; va[6] = (f16)x1.z; va[7] = (f16)x1.w;
      vb[0] = (f16)y0.x; vb[1] = (f16)y0.y; vb[2] = (f16)y0.z; vb[3] = (f16)y0.w;
      vb[4] = (f16)y1.x; vb[5] = (f16)y1.y; vb[6] = (f16)y1.z; vb[7] = (f16)y1.w;
      *(f16x8*)&As[e0 ^ xst] = va;
      *(f16x8*)&As[e1 ^ xst] = vb;
    }
    __syncthreads();

    f16x8 a[4], b[4];
#pragma unroll
    for (int i = 0; i < 4; ++i)
      a[i] = *(const f16x8*)&As[(((wm + i * 16 + fr) * 32) + fq * 8) ^ xrd];
#pragma unroll
    for (int j = 0; j < 4; ++j)
      b[j] = *(const f16x8*)&Ws[(((wn + j * 16 + fr) * 32) + fq * 8) ^ xrd];
#pragma unroll
    for (int i = 0; i < 4; ++i)
#pragma unroll
      for (int j = 0; j < 4; ++j)
        acc[i][j] = __builtin_amdgcn_mfma_f32_16x16x32_f16(a[i], b[j], acc[i][j], 0, 0, 0);
    __syncthreads();
  }

#pragma unroll
  for (int j = 0; j < 4; ++j) {
    const int col = n0 + wn + j * 16 + fr;
    const float bv = bias[col];
#pragma unroll
    for (int i = 0; i < 4; ++i) {
#pragma unroll
      for (int r = 0; r < 4; ++r) {
        const int row = m0 + wm + i * 16 + fq * 4 + r;
        C[(size_t)row * DD + col] = (f16)(acc[i][j][r] + bv);
      }
    }
  }
}

// ---------------- attn4: 8-phase-style pipelined QK^T row-stats -----------
// Grid 256: bid = qs*16 + bb*2 + kh. Block 512 thr = 8 waves (2q x 4k),
// block tile 256q x 256k, per-wave 128q x 64k (8x4 16x16x32 frags).
// d split into 192 half-tiles of 32; ring of 4 LDS half-slots per operand,
// 2 half-tiles prefetched ahead; per half-tile 2 phases, each:
// {ds_read cluster | 2 gload_lds -> barrier -> lgkm(0) -> setprio+16 MFMA ->
//  barrier}; counted vmcnt(4) once per half-tile (never 0 in steady loop).
__global__ __launch_bounds__(512, 2)
void attn4(const f16* __restrict__ Q, const f16* __restrict__ K,
           const int* __restrict__ mask, float* __restrict__ pmv,
           float* __restrict__ pzv, float* __restrict__ sdg) {
  __shared__ f16 Qs[4][256 * 32];
  __shared__ f16 Ks[4][256 * 32];
  __shared__ float pms[4][256];
  __shared__ float pzs[4][256];

  const int bid = blockIdx.x;
  const int qs = bid >> 4, bb = (bid >> 1) & 7, kh = bid & 1;
  const int t = threadIdx.x, l = t & 63, w = t >> 6;
  const int wq = w >> 2, wk = w & 3;
  const int fr = l & 15, fq = l >> 4;
  const int q0 = qs * 256;
  const float scale = 0.036084391824351613f;  // 1/sqrt(768)

  const f16* Qg = Q + ((size_t)bb * TT + q0) * DD;
  const f16* Kg = K + ((size_t)bb * TT + kh * 2048) * DD;

  // staging: thread t -> linear 16B slot L = w*64+l (rows 16w..16w+15) and
  // L+512 (rows 128+16w..). Source col pre-swizzled: c8 = ((l&3)^((l>>3)&3))*8.
  const int c8 = ((l & 3) ^ ((l >> 3) & 3)) * 8;
  const f16* qlo = Qg + (size_t)(16 * w + (l >> 2)) * DD + c8;
  const f16* qhi = qlo + (size_t)128 * DD;
  const f16* klo = Kg + (size_t)(16 * w + (l >> 2)) * DD + c8;
  const f16* khi = klo + (size_t)128 * DD;

  // fragment read: row*32 + (fq ^ ((fr>>1)&3))*8  (<=2-way banks = free)
  const int sx = (fq ^ ((fr >> 1) & 3)) * 8;
  const int abase = (wq * 128 + fr) * 32 + sx;
  const int bbase = (wk * 64 + fr) * 32 + sx;

  f32x4 acc[8][4] = {};
  float rmv = -1e30f, rzv = 0.f;
  int im0 = 1, im1 = 1, im2 = 1, im3 = 1;

  // prologue: stage half-slots 0 (oldest) then 1
  gload16(qlo,      &Qs[0][w * 512]);
  gload16(qhi,      &Qs[0][4096 + w * 512]);
  gload16(klo,      &Ks[0][w * 512]);
  gload16(khi,      &Ks[0][4096 + w * 512]);
  gload16(qlo + 32, &Qs[1][w * 512]);
  gload16(qhi + 32, &Qs[1][4096 + w * 512]);
  gload16(klo + 32, &Ks[1][w * 512]);
  gload16(khi + 32, &Ks[1][4096 + w * 512]);
  asm volatile("s_waitcnt vmcnt(4)" ::: "memory");
  __builtin_amdgcn_s_barrier();

  for (int h = 0; h < 192; ++h) {
    const int sl = h & 3;
    const int nh = h + 2;
    const bool stg = (nh < 192);
    const int d2 = (nh % 24) * 32;
    const size_t koff = (size_t)(nh / 24) * 256 * DD + d2;
    const f16* Qsl = &Qs[sl][0];
    const f16* Ksl = &Ks[sl][0];

    // ---- phase A: read bv[0..4]+av[0..4], stage Q(nh), 16 MFMA ----
    if ((h % 24) == 0) {  // preload mask for this kt (consumed at h%24==23)
      const int kb = bb * TT + kh * 2048 + (h / 24) * 256 + wk * 64 + fr;
      im0 = mask[kb]; im1 = mask[kb + 16]; im2 = mask[kb + 32]; im3 = mask[kb + 48];
    }
    f16x8 bv[4], av[4];
#pragma unroll
    for (int j = 0; j < 4; ++j) bv[j] = *(const f16x8*)&Ksl[bbase + j * 512];
#pragma unroll
    for (int i = 0; i < 4; ++i) av[i] = *(const f16x8*)&Qsl[abase + i * 512];
    if (stg) {
      gload16(qlo + d2, &Qs[nh & 3][w * 512]);
      gload16(qhi + d2, &Qs[nh & 3][4096 + w * 512]);
    }
    __builtin_amdgcn_s_barrier();
    asm volatile("s_waitcnt lgkmcnt(0)" ::: "memory");
    __builtin_amdgcn_sched_barrier(0);
    __builtin_amdgcn_s_setprio(1);
#pragma unroll
    for (int i = 0; i < 4; ++i)
#pragma unroll
      for (int j = 0; j < 4; ++j)
        acc[i][j] = __builtin_amdgcn_mfma_f32_16x16x32_f16(av[i], bv[j], acc[i][j], 0, 0, 0);
    __builtin_amdgcn_s_setprio(0);
    __builtin_amdgcn_sched_barrier(0);
    __builtin_amdgcn_s_barrier();

    // ---- phase B: read av[4..8], stage K(nh), 16 MFMA, vmcnt(4) ----
#pragma unroll
    for (int i = 0; i < 4; ++i) av[i] = *(const f16x8*)&Qsl[abase + (i + 4) * 512];
    if (stg) {
      gload16(klo + koff, &Ks[nh & 3][w * 512]);
      gload16(khi + koff, &Ks[nh & 3][4096 + w * 512]);
    }
    __builtin_amdgcn_s_barrier();
    asm volatile("s_waitcnt lgkmcnt(0)" ::: "memory");
    __builtin_amdgcn_sched_barrier(0);
    __builtin_amdgcn_s_setprio(1);
#pragma unroll
    for (int i = 0; i < 4; ++i)
#pragma unroll
      for (int j = 0; j < 4; ++j)
        acc[i + 4][j] = __builtin_amdgcn_mfma_f32_16x16x32_f16(av[i], bv[j], acc[i + 4][j], 0, 0, 0);
    __builtin_amdgcn_s_setprio(0);
    __builtin_amdgcn_sched_barrier(0);
    if (stg) asm volatile("s_waitcnt vmcnt(4)" ::: "memory");
    else     asm volatile("s_waitcnt vmcnt(0)" ::: "memory");
    __builtin_amdgcn_s_barrier();

    // ---- per-kt epilogue: softmax partial over this 256-col strip ----
    if ((h % 24) == 23) {
      const int kt = h / 24;
      const float mb0 = im0 ? 0.f : -1e30f;
      const float mb1 = im1 ? 0.f : -1e30f;
      const float mb2 = im2 ? 0.f : -1e30f;
      const float mb3 = im3 ? 0.f : -1e30f;
      const bool isdiag = (kh == (qs >> 3)) && (kt == (qs & 7));
#pragma unroll
      for (int i = 0; i < 8; ++i) {
#pragma unroll
        for (int rg = 0; rg < 4; ++rg) {
          float v0 = fmaf(acc[i][0][rg], scale, mb0);
          float v1 = fmaf(acc[i][1][rg], scale, mb1);
          float v2 = fmaf(acc[i][2][rg], scale, mb2);
          float v3 = fmaf(acc[i][3][rg], scale, mb3);
          if (isdiag) {
            const int rl = wq * 128 + i * 16 + fq * 4 + rg;
            const int cl = wk * 64 + fr;
            if (cl      == rl) sdg[(size_t)bb * TT + q0 + rl] = v0;
            if (cl + 16 == rl) sdg[(size_t)bb * TT + q0 + rl] = v1;
            if (cl + 32 == rl) sdg[(size_t)bb * TT + q0 + rl] = v2;
            if (cl + 48 == rl) sdg[(size_t)bb * TT + q0 + rl] = v3;
          }
          float mx = fmaxf(fmaxf(v0, v1), fmaxf(v2, v3));
#pragma unroll
          for (int off = 1; off < 16; off <<= 1)
            mx = fmaxf(mx, __shfl_xor(mx, off));
          float sz = __expf(v0 - mx) + __expf(v1 - mx) +
                     __expf(v2 - mx) + __expf(v3 - mx);
#pragma unroll
          for (int off = 1; off < 16; off <<= 1)
            sz += __shfl_xor(sz, off);
          if (fr == ((i * 4 + rg) & 15)) {
            const int row = wq * 128 + i * 16 + fq * 4 + rg;
            pms[wk][row] = mx;
            pzs[wk][row] = sz;
          }
        }
      }
#pragma unroll
      for (int i = 0; i < 8; ++i)
#pragma unroll
        for (int j = 0; j < 4; ++j)
          acc[i][j] = (f32x4)(0.f);
      asm volatile("s_waitcnt lgkmcnt(0)" ::: "memory");
      __builtin_amdgcn_sched_barrier(0);
      __builtin_amdgcn_s_barrier();
      if (t < 256) {
        float m0 = pms[0][t], m1 = pms[1][t], m2 = pms[2][t], m3 = pms[3][t];
        float m4 = fmaxf(fmaxf(m0, m1), fmaxf(m2, m3));
        float z4 = pzs[0][t] * __expf(m0 - m4) + pzs[1][t] * __expf(m1 - m4) +
                   pzs[2][t] * __expf(m2 - m4) + pzs[3][t] * __expf(m3 - m4);
        float mn = fmaxf(rmv, m4);
        rzv = rzv * __expf(rmv - mn) + z4 * __expf(m4 - mn);
        rmv = mn;
      }
      // pms/pzs rewritten only next kt (many barriers away) — safe
    }
  }

  if (t < 256) {
    pmv[(size_t)kh * MM + bb * TT + q0 + t] = rmv;
    pzv[(size_t)kh * MM + bb * TT + q0 + t] = rzv;
  }
}

// ---------------- merge 2 partials -> wdiag ----------------
__global__ void merge2(const float* __restrict__ pm, const float* __restrict__ pz,
                       const float* __restrict__ sdg, float* __restrict__ wdiag) {
  int i = blockIdx.x * 256 + threadIdx.x;
  if (i >= MM) return;
  float m0 = pm[i], m1 = pm[MM + i];
  float m = fmaxf(m0, m1);
  float Z = pz[i] * __expf(m0 - m) + pz[MM + i] * __expf(m1 - m);
  wdiag[i] = __expf(sdg[i] - m) / Z;
}

// ---------------- output ----------------
__global__ void zero_out(float* out, int n) {
  int i = blockIdx.x * 256 + threadIdx.x;
  if (i < n) out[i] = 0.f;
}

// out[b,d] = sum_t X[b,t,d] * wdiag[b,t]
__global__ __launch_bounds__(256)
void out_gemv(const float* __restrict__ X, const float* __restrict__ wdiag,
              float* __restrict__ out) {
  __shared__ float wsm[256];
  const int b = blockIdx.z;
  const int d = blockIdx.y * 256 + threadIdx.x;
  const int tbase = blockIdx.x * 256;
  wsm[threadIdx.x] = wdiag[b * TT + tbase + threadIdx.x];
  __syncthreads();
  float acc = 0.f;
  const float* xp = X + (size_t)(b * TT + tbase) * DD + d;
#pragma unroll 4
  for (int i = 0; i < 256; ++i) acc += xp[(size_t)i * DD] * wsm[i];
  atomicAdd(&out[b * DD + d], acc);
}

extern "C" void kernel_launch(void* const* d_in, const int* in_sizes, int n_in,
                              void* d_out, int out_size, void* d_ws, size_t ws_size,
                              hipStream_t stream) {
  const float* X    = (const float*)d_in[0];
  const int*   mask = (const int*)d_in[1];
  const float* Wq_w = (const float*)d_in[2];
  const float* Wq_b = (const float*)d_in[3];
  const float* Wk_w = (const float*)d_in[4];
  const float* Wk_b = (const float*)d_in[5];
  float* out = (float*)d_out;

  // workspace layout (~97 MB)
  f16* Qh  = (f16*)d_ws;
  f16* Kh  = Qh + (size_t)MM * DD;
  float* pm    = (float*)(Kh + (size_t)MM * DD);
  float* pz    = pm + 2 * (size_t)MM;
  float* sdg   = pz + 2 * (size_t)MM;
  float* wdiag = sdg + MM;

  proj_gemm<<<dim3(256, 6), 256, 0, stream>>>(X, Wq_w, Wq_b, Qh);
  proj_gemm<<<dim3(256, 6), 256, 0, stream>>>(X, Wk_w, Wk_b, Kh);

  attn4<<<256, 512, 0, stream>>>(Qh, Kh, mask, pm, pz, sdg);

  merge2<<<128, 256, 0, stream>>>(pm, pz, sdg, wdiag);

  zero_out<<<24, 256, 0, stream>>>(out, BB * DD);
  out_gemv<<<dim3(16, 3, 8), 256, 0, stream>>>(X, wdiag, out);
}

// Round 6
// 452.514 us; speedup vs baseline: 1.0488x; 1.0488x over previous
//
#include <hip/hip_runtime.h>

#define BB 8
#define TT 4096
#define DD 768
#define MM (BB*TT)   // 32768

typedef _Float16 f16;
typedef _Float16 f16x8 __attribute__((ext_vector_type(8)));
typedef float f32x4 __attribute__((ext_vector_type(4)));

typedef __attribute__((address_space(1))) void void_g;
typedef __attribute__((address_space(3))) void void_l;

// async global->LDS, 16B per lane. LDS dest = wave-uniform base + lane*16 (linear).
__device__ __forceinline__ void gload16(const void* g, void* l) {
  __builtin_amdgcn_global_load_lds((void_g*)g, (void_l*)l, 16, 0, 0);
}

// ---------------- projection GEMM: C[m,n] = sum_k A[m,k]*W[n,k] + bias[n] --
// A: MMxDD f32, W: DDxDD f32 (both converted to f16 during reg-staging)
__global__ __launch_bounds__(256)
void proj_gemm(const float* __restrict__ Af, const float* __restrict__ Wf,
               const float* __restrict__ bias, f16* __restrict__ C) {
  __shared__ f16 As[128 * 32];
  __shared__ f16 Ws[128 * 32];
  const int m0 = blockIdx.x * 128;
  const int n0 = blockIdx.y * 128;
  const int t = threadIdx.x;
  const int lane = t & 63;
  const int w = t >> 6;
  const int wm = (w >> 1) * 64;
  const int wn = (w & 1) * 64;
  const int fr = lane & 15, fq = lane >> 4;
  const int xst = ((t >> 3) & 3) << 3;   // store-side swizzle (row = t>>2)
  const int xrd = ((fr >> 1) & 3) << 3;  // read-side swizzle (row = ..+fr)

  f32x4 acc[4][4] = {};

  const int e0 = t * 8;
  const int r0 = t >> 2, cW = (t & 3) * 8;
  const int e1 = 2048 + t * 8;

  for (int ks = 0; ks < 24; ++ks) {
    const int k0 = ks * 32;
    {
      const float* g0 = Wf + (size_t)(n0 + r0) * DD + k0 + cW;
      const float* g1 = Wf + (size_t)(n0 + 64 + r0) * DD + k0 + cW;
      float4 x0 = *(const float4*)g0, x1 = *(const float4*)(g0 + 4);
      float4 y0 = *(const float4*)g1, y1 = *(const float4*)(g1 + 4);
      f16x8 va, vb;
      va[0] = (f16)x0.x; va[1] = (f16)x0.y; va[2] = (f16)x0.z; va[3] = (f16)x0.w;
      va[4] = (f16)x1.x; va[5] = (f16)x1.y; va[6] = (f16)x1.z; va[7] = (f16)x1.w;
      vb[0] = (f16)y0.x; vb[1] = (f16)y0.y; vb[2] = (f16)y0.z; vb[3] = (f16)y0.w;
      vb[4] = (f16)y1.x; vb[5] = (f16)y1.y; vb[6] = (f16)y1.z; vb[7] = (f16)y1.w;
      *(f16x8*)&Ws[e0 ^ xst] = va;
      *(f16x8*)&Ws[e1 ^ xst] = vb;
    }
    {
      const float* g0 = Af + (size_t)(m0 + r0) * DD + k0 + cW;
      const float* g1 = Af + (size_t)(m0 + 64 + r0) * DD + k0 + cW;
      float4 x0 = *(const float4*)g0, x1 = *(const float4*)(g0 + 4);
      float4 y0 = *(const float4*)g1, y1 = *(const float4*)(g1 + 4);
      f16x8 va, vb;
      va[0] = (f16)x0.x; va[1] = (f16)x0.y; va[2] = (f16)x0.z; va[3] = (f16)x0.w;
      va[4] = (f16)x1.x; va[5] = (f16)x1.y; va[6] = (f16)x1.z; va[7] = (f16)x1.w;
      vb[0] = (f16)y0.x; vb[1] = (f16)y0.y; vb[2] = (f16)y0.z; vb[3] = (f16)y0.w;
      vb[4] = (f16)y1.x; vb[5] = (f16)y1.y; vb[6] = (f16)y1.z; vb[7] = (f16)y1.w;
      *(f16x8*)&As[e0 ^ xst] = va;
      *(f16x8*)&As[e1 ^ xst] = vb;
    }
    __syncthreads();

    f16x8 a[4], b[4];
#pragma unroll
    for (int i = 0; i < 4; ++i)
      a[i] = *(const f16x8*)&As[(((wm + i * 16 + fr) * 32) + fq * 8) ^ xrd];
#pragma unroll
    for (int j = 0; j < 4; ++j)
      b[j] = *(const f16x8*)&Ws[(((wn + j * 16 + fr) * 32) + fq * 8) ^ xrd];
#pragma unroll
    for (int i = 0; i < 4; ++i)
#pragma unroll
      for (int j = 0; j < 4; ++j)
        acc[i][j] = __builtin_amdgcn_mfma_f32_16x16x32_f16(a[i], b[j], acc[i][j], 0, 0, 0);
    __syncthreads();
  }

#pragma unroll
  for (int j = 0; j < 4; ++j) {
    const int col = n0 + wn + j * 16 + fr;
    const float bv = bias[col];
#pragma unroll
    for (int i = 0; i < 4; ++i) {
#pragma unroll
      for (int r = 0; r < 4; ++r) {
        const int row = m0 + wm + i * 16 + fq * 4 + r;
        C[(size_t)row * DD + col] = (f16)(acc[i][j][r] + bv);
      }
    }
  }
}

// ---------------- attn5: 4-blocks/CU latency-hiding QK^T row-stats --------
// Grid 1024: bid = qs*32 + kh*8 + bb  (batch bb -> XCD bb). Block 256 thr =
// 4 waves (2q x 2k), tile 128q x 128k, kh quarter = 1024 k-cols (kt=0..7).
// LDS 33KB (Q/K dbuf-2) -> 4 blocks/CU; cross-block overlap hides the
// per-block barrier/LDS/MFMA serialization (m97 mechanism).
__global__ __launch_bounds__(256, 4)
void attn5(const f16* __restrict__ Q, const f16* __restrict__ K,
           const int* __restrict__ mask, float* __restrict__ pmv,
           float* __restrict__ pzv, float* __restrict__ sdg) {
  __shared__ f16 Qs[2][128 * 32];
  __shared__ f16 Ks[2][128 * 32];
  __shared__ float pms[2][128];
  __shared__ float pzs[2][128];

  const int bid = blockIdx.x;
  const int qs = bid >> 5, kh = (bid >> 3) & 3, bb = bid & 7;
  const int t = threadIdx.x, l = t & 63, w = t >> 6;
  const int wq = w >> 1, wk = w & 1;
  const int fr = l & 15, fq = l >> 4;
  const int q0 = qs * 128;
  const float scale = 0.036084391824351613f;  // 1/sqrt(768)

  const f16* Qg = Q + ((size_t)bb * TT + q0) * DD;
  const f16* Kg = K + ((size_t)bb * TT + kh * 1024) * DD;

  // staging: thread t -> linear 16B slots t (rows 0..63) and t+256 (rows 64..127).
  // source col-slot pre-swizzled: slot ^ ((row>>1)&3), row = t>>2.
  const int c8 = ((t & 3) ^ ((t >> 3) & 3)) * 8;
  const f16* qlo = Qg + (size_t)(t >> 2) * DD + c8;
  const f16* qhi = qlo + (size_t)64 * DD;
  const f16* klo = Kg + (size_t)(t >> 2) * DD + c8;
  const f16* khi = klo + (size_t)64 * DD;

  // fragment read: row*32 + (fq ^ ((fr>>1)&3))*8  (measured conflict-free)
  const int sx = (fq ^ ((fr >> 1) & 3)) * 8;
  const int abase = (wq * 64 + fr) * 32 + sx;
  const int bbase = (wk * 64 + fr) * 32 + sx;

  f32x4 acc[4][4] = {};
  float rmv = -1e30f, rzv = 0.f;
  int im0 = 1, im1 = 1, im2 = 1, im3 = 1;

#define STAGE(bf, kt_, d0_) do { \
    gload16(qlo + (d0_), &Qs[bf][w * 512]); \
    gload16(qhi + (d0_), &Qs[bf][2048 + w * 512]); \
    gload16(klo + (size_t)(kt_) * 128 * DD + (d0_), &Ks[bf][w * 512]); \
    gload16(khi + (size_t)(kt_) * 128 * DD + (d0_), &Ks[bf][2048 + w * 512]); \
  } while (0)

  STAGE(0, 0, 0);
  __syncthreads();

  for (int h = 0; h < 192; ++h) {
    const int buf = h & 1;
    const int kt = h / 24, dc = h % 24;
    if (h + 1 < 192) {
      const int nh = h + 1;
      STAGE(buf ^ 1, nh / 24, (nh % 24) * 32);
    }
    if (dc == 0) {  // preload mask for this kt (consumed at dc==23)
      const int kb = bb * TT + kh * 1024 + kt * 128 + wk * 64 + fr;
      im0 = mask[kb]; im1 = mask[kb + 16]; im2 = mask[kb + 32]; im3 = mask[kb + 48];
    }

    f16x8 bv[4];
#pragma unroll
    for (int j = 0; j < 4; ++j) bv[j] = *(const f16x8*)&Ks[buf][bbase + j * 512];
#pragma unroll
    for (int i = 0; i < 4; ++i) {
      f16x8 av = *(const f16x8*)&Qs[buf][abase + i * 512];
#pragma unroll
      for (int j = 0; j < 4; ++j)
        acc[i][j] = __builtin_amdgcn_mfma_f32_16x16x32_f16(av, bv[j], acc[i][j], 0, 0, 0);
    }

    if (dc == 23) {
      // ---- per-kt epilogue: softmax partial over this 128-col strip ----
      const float mb0 = im0 ? 0.f : -1e30f;
      const float mb1 = im1 ? 0.f : -1e30f;
      const float mb2 = im2 ? 0.f : -1e30f;
      const float mb3 = im3 ? 0.f : -1e30f;
      const bool isdiag = (kh == (qs >> 3)) && (kt == (qs & 7));
#pragma unroll
      for (int i = 0; i < 4; ++i) {
#pragma unroll
        for (int rg = 0; rg < 4; ++rg) {
          float v0 = fmaf(acc[i][0][rg], scale, mb0);
          float v1 = fmaf(acc[i][1][rg], scale, mb1);
          float v2 = fmaf(acc[i][2][rg], scale, mb2);
          float v3 = fmaf(acc[i][3][rg], scale, mb3);
          if (isdiag) {
            const int rl = wq * 64 + i * 16 + fq * 4 + rg;
            const int cl = wk * 64 + fr;
            if (cl      == rl) sdg[(size_t)bb * TT + q0 + rl] = v0;
            if (cl + 16 == rl) sdg[(size_t)bb * TT + q0 + rl] = v1;
            if (cl + 32 == rl) sdg[(size_t)bb * TT + q0 + rl] = v2;
            if (cl + 48 == rl) sdg[(size_t)bb * TT + q0 + rl] = v3;
          }
          float mx = fmaxf(fmaxf(v0, v1), fmaxf(v2, v3));
#pragma unroll
          for (int off = 1; off < 16; off <<= 1)
            mx = fmaxf(mx, __shfl_xor(mx, off));
          float sz = __expf(v0 - mx) + __expf(v1 - mx) +
                     __expf(v2 - mx) + __expf(v3 - mx);
#pragma unroll
          for (int off = 1; off < 16; off <<= 1)
            sz += __shfl_xor(sz, off);
          if (fr == ((i * 4 + rg) & 15)) {
            const int row = wq * 64 + i * 16 + fq * 4 + rg;
            pms[wk][row] = mx;
            pzs[wk][row] = sz;
          }
        }
      }
#pragma unroll
      for (int i = 0; i < 4; ++i)
#pragma unroll
        for (int j = 0; j < 4; ++j)
          acc[i][j] = (f32x4)(0.f);
      __syncthreads();
      if (t < 128) {
        float m0 = pms[0][t], m1 = pms[1][t];
        float m2 = fmaxf(m0, m1);
        float z2 = pzs[0][t] * __expf(m0 - m2) + pzs[1][t] * __expf(m1 - m2);
        float mn = fmaxf(rmv, m2);
        rzv = rzv * __expf(rmv - mn) + z2 * __expf(m2 - mn);
        rmv = mn;
      }
      // pms/pzs rewritten only next kt (24 barriers away) — safe
    }

    __syncthreads();
  }
#undef STAGE

  if (t < 128) {
    pmv[(size_t)kh * MM + bb * TT + q0 + t] = rmv;
    pzv[(size_t)kh * MM + bb * TT + q0 + t] = rzv;
  }
}

// ---------------- merge 4 partials -> wdiag ----------------
__global__ void merge4(const float* __restrict__ pm, const float* __restrict__ pz,
                       const float* __restrict__ sdg, float* __restrict__ wdiag) {
  int i = blockIdx.x * 256 + threadIdx.x;
  if (i >= MM) return;
  float m0 = pm[i], m1 = pm[MM + i], m2 = pm[2 * MM + i], m3 = pm[3 * MM + i];
  float m = fmaxf(fmaxf(m0, m1), fmaxf(m2, m3));
  float Z = pz[i] * __expf(m0 - m) + pz[MM + i] * __expf(m1 - m) +
            pz[2 * MM + i] * __expf(m2 - m) + pz[3 * MM + i] * __expf(m3 - m);
  wdiag[i] = __expf(sdg[i] - m) / Z;
}

// ---------------- output ----------------
__global__ void zero_out(float* out, int n) {
  int i = blockIdx.x * 256 + threadIdx.x;
  if (i < n) out[i] = 0.f;
}

// out[b,d] = sum_t X[b,t,d] * wdiag[b,t]
__global__ __launch_bounds__(256)
void out_gemv(const float* __restrict__ X, const float* __restrict__ wdiag,
              float* __restrict__ out) {
  __shared__ float wsm[256];
  const int b = blockIdx.z;
  const int d = blockIdx.y * 256 + threadIdx.x;
  const int tbase = blockIdx.x * 256;
  wsm[threadIdx.x] = wdiag[b * TT + tbase + threadIdx.x];
  __syncthreads();
  float acc = 0.f;
  const float* xp = X + (size_t)(b * TT + tbase) * DD + d;
#pragma unroll 4
  for (int i = 0; i < 256; ++i) acc += xp[(size_t)i * DD] * wsm[i];
  atomicAdd(&out[b * DD + d], acc);
}

extern "C" void kernel_launch(void* const* d_in, const int* in_sizes, int n_in,
                              void* d_out, int out_size, void* d_ws, size_t ws_size,
                              hipStream_t stream) {
  const float* X    = (const float*)d_in[0];
  const int*   mask = (const int*)d_in[1];
  const float* Wq_w = (const float*)d_in[2];
  const float* Wq_b = (const float*)d_in[3];
  const float* Wk_w = (const float*)d_in[4];
  const float* Wk_b = (const float*)d_in[5];
  float* out = (float*)d_out;

  // workspace layout (~98 MB)
  f16* Qh  = (f16*)d_ws;
  f16* Kh  = Qh + (size_t)MM * DD;
  float* pm    = (float*)(Kh + (size_t)MM * DD);
  float* pz    = pm + 4 * (size_t)MM;
  float* sdg   = pz + 4 * (size_t)MM;
  float* wdiag = sdg + MM;

  proj_gemm<<<dim3(256, 6), 256, 0, stream>>>(X, Wq_w, Wq_b, Qh);
  proj_gemm<<<dim3(256, 6), 256, 0, stream>>>(X, Wk_w, Wk_b, Kh);

  attn5<<<1024, 256, 0, stream>>>(Qh, Kh, mask, pm, pz, sdg);

  merge4<<<128, 256, 0, stream>>>(pm, pz, sdg, wdiag);

  zero_out<<<24, 256, 0, stream>>>(out, BB * DD);
  out_gemv<<<dim3(16, 3, 8), 256, 0, stream>>>(X, wdiag, out);
}